// Round 1
// baseline (513.062 us; speedup 1.0000x reference)
//
#include <hip/hip_runtime.h>

// Problem constants: x[16,4096,512] fp32 -> windows [1024, 64, 512]
//   qkv = xw @ Wqkv[512,1536]; per head (8 x 64d): S = QK^T/8, causal mask,
//   softmax, softmax AGAIN (no re-mask: masked entries are 0 -> exp(0)=1),
//   out = P2 @ V; concat heads; out @ Wproj + bproj.  Output fp32.

typedef _Float16 f16x8 __attribute__((ext_vector_type(8)));
typedef float f32x4 __attribute__((ext_vector_type(4)));

#define MFMA16(a, b, c) __builtin_amdgcn_mfma_f32_16x16x32_f16((a), (b), (c), 0, 0, 0)

// XOR-swizzled element index (fp16 elements). Row stride 64 elems (128 B) or
// 512 elems (1 KB); both are multiples of 128 B -> 16-way bank conflicts if
// linear. byte ^= (row&7)<<4  ==  elem ^= (row&7)<<3.
__device__ __forceinline__ int swz64(int r, int c) { return r * 64 + (c ^ ((r & 7) << 3)); }
__device__ __forceinline__ int swz512(int r, int c) { return r * 512 + (c ^ ((r & 7) << 3)); }

// ---------------------------------------------------------------------------
// Prep: fp32 weights -> fp16 transposed copies in workspace.
//   wqkvT[c][k] = Wqkv[k][c] * (c < 512 ? 0.125 : 1)   [1536 x 512]
//   wprojT[n][k] = Wproj[k][n]                          [512 x 512]
// ---------------------------------------------------------------------------
__global__ void prep_weights(const float* __restrict__ Wqkv,
                             const float* __restrict__ Wproj,
                             _Float16* __restrict__ wqkvT,
                             _Float16* __restrict__ wprojT) {
  int idx = blockIdx.x * blockDim.x + threadIdx.x;
  if (idx < 512 * 1536) {
    int k = idx / 1536, c = idx - k * 1536;
    float v = Wqkv[idx];
    if (c < 512) v *= 0.125f;  // fold attention scale hd^-0.5 into Q weights
    wqkvT[c * 512 + k] = (_Float16)v;
  } else {
    int j = idx - 512 * 1536;  // [0, 262144)
    int k = j >> 9, n = j & 511;
    wprojT[n * 512 + k] = (_Float16)Wproj[j];
  }
}

// ---------------------------------------------------------------------------
// Fused per-window kernel. 1 block = 1 window (64 tokens). 512 threads.
// ---------------------------------------------------------------------------
__global__ __launch_bounds__(512, 2) void attn_fused(
    const float* __restrict__ x, const _Float16* __restrict__ wqkvT,
    const _Float16* __restrict__ wprojT, const float* __restrict__ bproj,
    float* __restrict__ out) {
  __shared__ _Float16 sX[64 * 512];     // 64 KB: window activations, fp16
  __shared__ _Float16 sQ[2][64 * 64];   // per head in pair: Q [token][d]
  __shared__ _Float16 sK[2][64 * 64];   // K [token][d]
  __shared__ _Float16 sVT[2][64 * 64];  // V transposed [d][token]
  __shared__ _Float16 sPO[2][64 * 64];  // P2 [q][k], then reused as out_h [token][d]

  const int tid = threadIdx.x;
  const int wid = tid >> 6;   // wave 0..7
  const int lane = tid & 63;
  const int lg = lane >> 4;   // lane group 0..3 (k-chunk / C-row-group)
  const int lr = lane & 15;   // lane row/col within tile

  // ---- stage X window: fp32 global -> fp16 LDS (swizzled) ----
  const float4* xv = (const float4*)(x + (size_t)blockIdx.x * (64 * 512));
#pragma unroll
  for (int it = 0; it < 8; ++it) {
    int g = tid + it * 512;           // chunk of 8 floats; 4096 chunks total
    int r = g >> 6, c0 = (g & 63) << 3;
    float4 a = xv[(r << 7) + (c0 >> 2)];
    float4 b = xv[(r << 7) + (c0 >> 2) + 1];
    f16x8 hv;
    hv[0] = (_Float16)a.x; hv[1] = (_Float16)a.y;
    hv[2] = (_Float16)a.z; hv[3] = (_Float16)a.w;
    hv[4] = (_Float16)b.x; hv[5] = (_Float16)b.y;
    hv[6] = (_Float16)b.z; hv[7] = (_Float16)b.w;
    *(f16x8*)&sX[swz512(r, c0)] = hv;
  }

  const f32x4 zero4 = {0.f, 0.f, 0.f, 0.f};
  // projection accumulator: this wave owns out[all 64 rows][wid*64 .. +64)
  f32x4 accO[4][4];
#pragma unroll
  for (int i = 0; i < 4; ++i)
#pragma unroll
    for (int j = 0; j < 4; ++j) accO[i][j] = zero4;

  __syncthreads();

  for (int hp = 0; hp < 4; ++hp) {  // head pairs (heads 2hp, 2hp+1)
    // ================= Phase A: QKV projection (col-strips) =================
    // 24 units = {head in pair} x {q,k,v} x {16-col strip}; 3 units per wave.
    int hu[3], su[3], stu[3];
    const _Float16* bptr[3];
    f32x4 acc[3][4];
#pragma unroll
    for (int i = 0; i < 3; ++i) {
      int u = wid + 8 * i;
      int hh = u & 1, v2 = u >> 1;       // v2 in [0,12)
      int sec = v2 % 3, strip = v2 / 3;  // sec: 0=Q 1=K 2=V
      hu[i] = hh; su[i] = sec; stu[i] = strip;
      bptr[i] = wqkvT +
                ((size_t)(sec * 512 + (hp * 2 + hh) * 64 + strip * 16 + lr)) * 512 +
                lg * 8;
#pragma unroll
      for (int rt = 0; rt < 4; ++rt) acc[i][rt] = zero4;
    }
#pragma unroll
    for (int ks = 0; ks < 16; ++ks) {
      f16x8 af[4];  // A fragments shared by all 3 units (same rows, same k)
#pragma unroll
      for (int rt = 0; rt < 4; ++rt)
        af[rt] = *(const f16x8*)&sX[swz512(rt * 16 + lr, ks * 32 + lg * 8)];
#pragma unroll
      for (int i = 0; i < 3; ++i) {
        f16x8 bf = *(const f16x8*)(bptr[i] + ks * 32);
#pragma unroll
        for (int rt = 0; rt < 4; ++rt) acc[i][rt] = MFMA16(af[rt], bf, acc[i][rt]);
      }
    }
    // scatter results to LDS (C layout: row=(lg*4+rg), col=lr within tile)
#pragma unroll
    for (int i = 0; i < 3; ++i) {
      int hh = hu[i], sec = su[i], strip = stu[i];
#pragma unroll
      for (int rt = 0; rt < 4; ++rt)
#pragma unroll
        for (int rg = 0; rg < 4; ++rg) {
          int row = rt * 16 + lg * 4 + rg;  // token
          int col = strip * 16 + lr;        // d
          _Float16 v = (_Float16)acc[i][rt][rg];
          if (sec == 0) sQ[hh][swz64(row, col)] = v;
          else if (sec == 1) sK[hh][swz64(row, col)] = v;
          else sVT[hh][swz64(col, row)] = v;  // store V transposed
        }
    }
    __syncthreads();  // barrier 1: Q/K/V ready

    // ============ Phase B: S = QK^T, double softmax, PV (row-strips) ========
    {
      const int hh = wid >> 2;  // waves 0-3 -> head 0, waves 4-7 -> head 1
      const int rs = wid & 3;   // 16-row strip
      f32x4 sacc[4];
#pragma unroll
      for (int nt = 0; nt < 4; ++nt) sacc[nt] = zero4;
#pragma unroll
      for (int ks = 0; ks < 2; ++ks) {
        f16x8 af = *(const f16x8*)&sQ[hh][swz64(rs * 16 + lr, ks * 32 + lg * 8)];
#pragma unroll
        for (int nt = 0; nt < 4; ++nt) {
          f16x8 bf = *(const f16x8*)&sK[hh][swz64(nt * 16 + lr, ks * 32 + lg * 8)];
          sacc[nt] = MFMA16(af, bf, sacc[nt]);
        }
      }
      // double softmax, fp32. Lane holds S[rs*16+lg*4+rg][nt*16+lr].
      float p2[4][4];
#pragma unroll
      for (int rg = 0; rg < 4; ++rg) {
        int row = rs * 16 + lg * 4 + rg;
        float m = -1e30f;
#pragma unroll
        for (int nt = 0; nt < 4; ++nt) {
          int col = nt * 16 + lr;
          float v = (col <= row) ? sacc[nt][rg] : -1e30f;
          m = fmaxf(m, v);
        }
#pragma unroll
        for (int off = 8; off >= 1; off >>= 1) m = fmaxf(m, __shfl_xor(m, off));
        float e[4], s1 = 0.f;
#pragma unroll
        for (int nt = 0; nt < 4; ++nt) {
          int col = nt * 16 + lr;
          e[nt] = (col <= row) ? __expf(sacc[nt][rg] - m) : 0.f;
          s1 += e[nt];
        }
#pragma unroll
        for (int off = 8; off >= 1; off >>= 1) s1 += __shfl_xor(s1, off);
        float inv1 = 1.f / s1;
        // second softmax on probabilities, NO re-mask (masked -> exp(0)=1)
        float e2[4], s2 = 0.f;
#pragma unroll
        for (int nt = 0; nt < 4; ++nt) {
          e2[nt] = __expf(e[nt] * inv1);
          s2 += e2[nt];
        }
#pragma unroll
        for (int off = 8; off >= 1; off >>= 1) s2 += __shfl_xor(s2, off);
        float inv2 = 1.f / s2;
#pragma unroll
        for (int nt = 0; nt < 4; ++nt) p2[nt][rg] = e2[nt] * inv2;
      }
      // write P2 (wave-private rows; same-wave in-order LDS, no barrier)
#pragma unroll
      for (int nt = 0; nt < 4; ++nt)
#pragma unroll
        for (int rg = 0; rg < 4; ++rg)
          sPO[hh][swz64(rs * 16 + lg * 4 + rg, nt * 16 + lr)] = (_Float16)p2[nt][rg];
      asm volatile("" ::: "memory");
      // PV: out_h rows strip = P2[rows][k] @ V[k][d] (B from sVT rows = d)
      f32x4 oacc[4];
#pragma unroll
      for (int nt = 0; nt < 4; ++nt) oacc[nt] = zero4;
#pragma unroll
      for (int ks = 0; ks < 2; ++ks) {
        f16x8 af = *(const f16x8*)&sPO[hh][swz64(rs * 16 + lr, ks * 32 + lg * 8)];
#pragma unroll
        for (int nt = 0; nt < 4; ++nt) {
          f16x8 bf = *(const f16x8*)&sVT[hh][swz64(nt * 16 + lr, ks * 32 + lg * 8)];
          oacc[nt] = MFMA16(af, bf, oacc[nt]);
        }
      }
      asm volatile("" ::: "memory");
      // overwrite sPO with out_h [token][d] (same wave-private rows)
#pragma unroll
      for (int nt = 0; nt < 4; ++nt)
#pragma unroll
        for (int rg = 0; rg < 4; ++rg)
          sPO[hh][swz64(rs * 16 + lg * 4 + rg, nt * 16 + lr)] = (_Float16)oacc[nt][rg];
    }
    __syncthreads();  // barrier 2: out_h ready

    // ================= Phase C: projection accumulate (col-strips) ==========
    // out[64][wid*64..+64) += out_h @ Wproj[h*64.., :]
#pragma unroll
    for (int hh = 0; hh < 2; ++hh) {
      const _Float16* pb = wprojT + ((size_t)(wid * 64 + lr)) * 512 +
                           (hp * 2 + hh) * 64 + lg * 8;
#pragma unroll
      for (int ks = 0; ks < 2; ++ks) {
        f16x8 af[4];
#pragma unroll
        for (int rt = 0; rt < 4; ++rt)
          af[rt] = *(const f16x8*)&sPO[hh][swz64(rt * 16 + lr, ks * 32 + lg * 8)];
#pragma unroll
        for (int nt = 0; nt < 4; ++nt) {
          f16x8 bf = *(const f16x8*)(pb + (size_t)nt * 16 * 512 + ks * 32);
#pragma unroll
          for (int rt = 0; rt < 4; ++rt)
            accO[rt][nt] = MFMA16(af[rt], bf, accO[rt][nt]);
        }
      }
    }
    // no barrier needed here: next phase A writes sQ/sK/sVT (readers finished
    // before barrier 2); sPO next written in phase B after its barrier 1.
  }

  // ======================= epilogue: bias + store ==========================
  size_t base = (size_t)blockIdx.x * (64 * 512);
#pragma unroll
  for (int nt = 0; nt < 4; ++nt) {
    int col = wid * 64 + nt * 16 + lr;
    float b = bproj[col];
#pragma unroll
    for (int rt = 0; rt < 4; ++rt)
#pragma unroll
      for (int rg = 0; rg < 4; ++rg) {
        int row = rt * 16 + lg * 4 + rg;
        out[base + (size_t)row * 512 + col] = accO[rt][nt][rg] + b;
      }
  }
}

extern "C" void kernel_launch(void* const* d_in, const int* in_sizes, int n_in,
                              void* d_out, int out_size, void* d_ws, size_t ws_size,
                              hipStream_t stream) {
  const float* x = (const float*)d_in[0];
  const float* Wqkv = (const float*)d_in[1];
  const float* Wproj = (const float*)d_in[2];
  const float* bproj = (const float*)d_in[3];
  float* out = (float*)d_out;

  _Float16* wqkvT = (_Float16*)d_ws;              // 1536*512 fp16 = 1.5 MB
  _Float16* wprojT = wqkvT + 512 * 1536;          // 512*512 fp16 = 0.5 MB

  prep_weights<<<dim3(4096), dim3(256), 0, stream>>>(Wqkv, Wproj, wqkvT, wprojT);
  attn_fused<<<dim3(1024), dim3(512), 0, stream>>>(x, wqkvT, wprojT, bproj, out);
}

// Round 2
// 471.706 us; speedup vs baseline: 1.0877x; 1.0877x over previous
//
#include <hip/hip_runtime.h>

// x[16,4096,512] fp32 -> windows [1024, 64, 512]
//   qkv = xw @ Wqkv[512,1536]; per head (8 x 64d): S = QK^T/8, causal mask,
//   softmax, softmax AGAIN (no re-mask), out = P2 @ V; concat; @ Wproj + bproj.

typedef _Float16 f16x8 __attribute__((ext_vector_type(8)));
typedef float f32x4 __attribute__((ext_vector_type(4)));

#define MFMA16(a, b, c) __builtin_amdgcn_mfma_f32_16x16x32_f16((a), (b), (c), 0, 0, 0)

__device__ __forceinline__ int swz64(int r, int c) { return r * 64 + (c ^ ((r & 7) << 3)); }
__device__ __forceinline__ int swz512(int r, int c) { return r * 512 + (c ^ ((r & 7) << 3)); }

// ---------------------------------------------------------------------------
// Prep: fp32 weights -> fp16 in MFMA B-fragment packed layout.
//   value(row, k) row = output col, k = reduction index:
//     wqkvP: W = Wqkv^T scaled (rows 0..1535), wprojP: W = Wproj^T (rows 0..511)
//   packed[r16][kt][lane][e] = value(r16*16 + (lane&15), kt*32 + (lane>>4)*8 + e)
//   -> one wave B-fragment load = contiguous 1KB.
// ---------------------------------------------------------------------------
__global__ void prep_weights(const float* __restrict__ Wqkv,
                             const float* __restrict__ Wproj,
                             _Float16* __restrict__ wqkvP,
                             _Float16* __restrict__ wprojP) {
  int idx = blockIdx.x * blockDim.x + threadIdx.x;
  if (idx < 786432) {
    int r16 = idx >> 13;
    int rem = idx & 8191;
    int kt = rem >> 9;
    int lane = (rem >> 3) & 63;
    int e = rem & 7;
    int row = r16 * 16 + (lane & 15);          // output col in [0,1536)
    int k = kt * 32 + (lane >> 4) * 8 + e;     // k in [0,512)
    float v = Wqkv[k * 1536 + row];
    if (row < 512) v *= 0.125f;                // fold hd^-0.5 into Q
    wqkvP[idx] = (_Float16)v;
  } else {
    int j = idx - 786432;                      // [0, 262144)
    int r16 = j >> 13;
    int rem = j & 8191;
    int kt = rem >> 9;
    int lane = (rem >> 3) & 63;
    int e = rem & 7;
    int n = r16 * 16 + (lane & 15);            // output col in [0,512)
    int k = kt * 32 + (lane >> 4) * 8 + e;
    wprojP[j] = (_Float16)Wproj[k * 512 + n];
  }
}

// ---------------------------------------------------------------------------
// Fused per-window kernel. 1 block = 1 window (64 tokens). 512 threads.
// ---------------------------------------------------------------------------
__global__ __launch_bounds__(512, 2) void attn_fused(
    const float* __restrict__ x, const _Float16* __restrict__ wqkvP,
    const _Float16* __restrict__ wprojP, const float* __restrict__ bproj,
    float* __restrict__ out) {
  __shared__ __align__(16) _Float16 sX[64 * 512];        // 64 KB
  __shared__ __align__(16) _Float16 sHeads[4][2][4096];  // 64 KB: Q,K,VT,PO x 2 heads

  const int tid = threadIdx.x;
  const int wid = tid >> 6;
  const int lane = tid & 63;
  const int lg = lane >> 4;
  const int lr = lane & 15;

  _Float16* sQ0 = &sHeads[0][0][0];
  _Float16* sQ1 = &sHeads[0][1][0];
  _Float16* sK0 = &sHeads[1][0][0];
  _Float16* sK1 = &sHeads[1][1][0];
  _Float16* sVT0 = &sHeads[2][0][0];
  _Float16* sVT1 = &sHeads[2][1][0];
  _Float16* sPO0 = &sHeads[3][0][0];
  _Float16* sPO1 = &sHeads[3][1][0];

  // ---- stage X window: fp32 global -> fp16 LDS (swizzled) ----
  const float4* xv = (const float4*)(x + (size_t)blockIdx.x * (64 * 512));
#pragma unroll
  for (int it = 0; it < 8; ++it) {
    int g = tid + it * 512;
    int r = g >> 6, c0 = (g & 63) << 3;
    float4 a = xv[(r << 7) + (c0 >> 2)];
    float4 b = xv[(r << 7) + (c0 >> 2) + 1];
    f16x8 hv;
    hv[0] = (_Float16)a.x; hv[1] = (_Float16)a.y;
    hv[2] = (_Float16)a.z; hv[3] = (_Float16)a.w;
    hv[4] = (_Float16)b.x; hv[5] = (_Float16)b.y;
    hv[6] = (_Float16)b.z; hv[7] = (_Float16)b.w;
    *(f16x8*)&sX[swz512(r, c0)] = hv;
  }

  const f32x4 zero4 = {0.f, 0.f, 0.f, 0.f};
  f32x4 accO[4][4];
#pragma unroll
  for (int i = 0; i < 4; ++i)
#pragma unroll
    for (int j = 0; j < 4; ++j) accO[i][j] = zero4;

  __syncthreads();

  for (int hp = 0; hp < 4; ++hp) {
    // ================= Phase A: QKV projection (col-strips) =================
    int hu[3], su[3], stu[3];
    const _Float16* bp[3];
    f32x4 acc[3][4];
#pragma unroll
    for (int i = 0; i < 3; ++i) {
      int u = wid + 8 * i;
      int hh = u & 1, v2 = u >> 1;
      int sec = v2 % 3, strip = v2 / 3;
      hu[i] = hh; su[i] = sec; stu[i] = strip;
      int r16 = sec * 32 + (hp * 2 + hh) * 4 + strip;
      bp[i] = wqkvP + (size_t)r16 * 8192 + lane * 8;
#pragma unroll
      for (int rt = 0; rt < 4; ++rt) acc[i][rt] = zero4;
    }
    // depth-3 B ring + double-buffered A frags
    f16x8 bf[3][3];
#pragma unroll
    for (int d = 0; d < 3; ++d)
#pragma unroll
      for (int i = 0; i < 3; ++i) bf[d][i] = *(const f16x8*)(bp[i] + d * 512);
    f16x8 af[2][4];
#pragma unroll
    for (int rt = 0; rt < 4; ++rt)
      af[0][rt] = *(const f16x8*)&sX[swz512(rt * 16 + lr, lg * 8)];
#pragma unroll
    for (int ks = 0; ks < 16; ++ks) {
      if (ks < 15) {
#pragma unroll
        for (int rt = 0; rt < 4; ++rt)
          af[(ks + 1) & 1][rt] =
              *(const f16x8*)&sX[swz512(rt * 16 + lr, (ks + 1) * 32 + lg * 8)];
      }
#pragma unroll
      for (int i = 0; i < 3; ++i)
#pragma unroll
        for (int rt = 0; rt < 4; ++rt)
          acc[i][rt] = MFMA16(af[ks & 1][rt], bf[ks % 3][i], acc[i][rt]);
      if (ks + 3 < 16) {
#pragma unroll
        for (int i = 0; i < 3; ++i)
          bf[ks % 3][i] = *(const f16x8*)(bp[i] + (ks + 3) * 512);
      }
    }
    // scatter results to LDS
#pragma unroll
    for (int i = 0; i < 3; ++i) {
      int hh = hu[i], sec = su[i], strip = stu[i];
      _Float16* dq = hh ? sQ1 : sQ0;
      _Float16* dk = hh ? sK1 : sK0;
      _Float16* dv = hh ? sVT1 : sVT0;
#pragma unroll
      for (int rt = 0; rt < 4; ++rt)
#pragma unroll
        for (int rg = 0; rg < 4; ++rg) {
          int row = rt * 16 + lg * 4 + rg;
          int col = strip * 16 + lr;
          _Float16 v = (_Float16)acc[i][rt][rg];
          if (sec == 0) dq[swz64(row, col)] = v;
          else if (sec == 1) dk[swz64(row, col)] = v;
          else dv[swz64(col, row)] = v;  // V transposed
        }
    }
    __syncthreads();  // barrier 1: Q/K/V ready

    // ============ Phase B: S = QK^T, double softmax, PV (row-strips) ========
    {
      const int hh = wid >> 2;
      const int rs = wid & 3;
      const _Float16* mQ = hh ? sQ1 : sQ0;
      const _Float16* mK = hh ? sK1 : sK0;
      const _Float16* mV = hh ? sVT1 : sVT0;
      _Float16* mP = hh ? sPO1 : sPO0;
      f32x4 sacc[4];
#pragma unroll
      for (int nt = 0; nt < 4; ++nt) sacc[nt] = zero4;
#pragma unroll
      for (int ks = 0; ks < 2; ++ks) {
        f16x8 afq = *(const f16x8*)&mQ[swz64(rs * 16 + lr, ks * 32 + lg * 8)];
#pragma unroll
        for (int nt = 0; nt < 4; ++nt) {
          f16x8 bfk = *(const f16x8*)&mK[swz64(nt * 16 + lr, ks * 32 + lg * 8)];
          sacc[nt] = MFMA16(afq, bfk, sacc[nt]);
        }
      }
      float p2[4][4];
#pragma unroll
      for (int rg = 0; rg < 4; ++rg) {
        int row = rs * 16 + lg * 4 + rg;
        float m = -1e30f;
#pragma unroll
        for (int nt = 0; nt < 4; ++nt) {
          int col = nt * 16 + lr;
          float v = (col <= row) ? sacc[nt][rg] : -1e30f;
          m = fmaxf(m, v);
        }
#pragma unroll
        for (int off = 8; off >= 1; off >>= 1) m = fmaxf(m, __shfl_xor(m, off));
        float e[4], s1 = 0.f;
#pragma unroll
        for (int nt = 0; nt < 4; ++nt) {
          int col = nt * 16 + lr;
          e[nt] = (col <= row) ? __expf(sacc[nt][rg] - m) : 0.f;
          s1 += e[nt];
        }
#pragma unroll
        for (int off = 8; off >= 1; off >>= 1) s1 += __shfl_xor(s1, off);
        float inv1 = 1.f / s1;
        float e2[4], s2 = 0.f;
#pragma unroll
        for (int nt = 0; nt < 4; ++nt) {
          e2[nt] = __expf(e[nt] * inv1);
          s2 += e2[nt];
        }
#pragma unroll
        for (int off = 8; off >= 1; off >>= 1) s2 += __shfl_xor(s2, off);
        float inv2 = 1.f / s2;
#pragma unroll
        for (int nt = 0; nt < 4; ++nt) p2[nt][rg] = e2[nt] * inv2;
      }
#pragma unroll
      for (int nt = 0; nt < 4; ++nt)
#pragma unroll
        for (int rg = 0; rg < 4; ++rg)
          mP[swz64(rs * 16 + lg * 4 + rg, nt * 16 + lr)] = (_Float16)p2[nt][rg];
      asm volatile("" ::: "memory");
      f32x4 oacc[4];
#pragma unroll
      for (int nt = 0; nt < 4; ++nt) oacc[nt] = zero4;
#pragma unroll
      for (int ks = 0; ks < 2; ++ks) {
        f16x8 afp = *(const f16x8*)&mP[swz64(rs * 16 + lr, ks * 32 + lg * 8)];
#pragma unroll
        for (int nt = 0; nt < 4; ++nt) {
          f16x8 bfv = *(const f16x8*)&mV[swz64(nt * 16 + lr, ks * 32 + lg * 8)];
          oacc[nt] = MFMA16(afp, bfv, oacc[nt]);
        }
      }
      asm volatile("" ::: "memory");
#pragma unroll
      for (int nt = 0; nt < 4; ++nt)
#pragma unroll
        for (int rg = 0; rg < 4; ++rg)
          mP[swz64(rs * 16 + lg * 4 + rg, nt * 16 + lr)] = (_Float16)oacc[nt][rg];
    }
    __syncthreads();  // barrier 2: out_h ready

    // ================= Phase C: projection accumulate (col-strips) ==========
    {
      f16x8 bfC[2][4], afC[2][4];
      const _Float16* po[2] = {sPO0, sPO1};
      // prologue g=0 (hh=0, ks=0)
#pragma unroll
      for (int rt = 0; rt < 4; ++rt)
        afC[0][rt] = *(const f16x8*)&po[0][swz64(rt * 16 + lr, lg * 8)];
#pragma unroll
      for (int nt = 0; nt < 4; ++nt)
        bfC[0][nt] = *(const f16x8*)(wprojP + (size_t)(wid * 4 + nt) * 8192 +
                                     (size_t)(hp * 4) * 512 + lane * 8);
#pragma unroll
      for (int g = 0; g < 4; ++g) {  // g = hh*2 + ks
        if (g < 3) {
          int hn = (g + 1) >> 1, kn = (g + 1) & 1;
#pragma unroll
          for (int rt = 0; rt < 4; ++rt)
            afC[(g + 1) & 1][rt] =
                *(const f16x8*)&po[hn][swz64(rt * 16 + lr, kn * 32 + lg * 8)];
#pragma unroll
          for (int nt = 0; nt < 4; ++nt)
            bfC[(g + 1) & 1][nt] =
                *(const f16x8*)(wprojP + (size_t)(wid * 4 + nt) * 8192 +
                                (size_t)(hp * 4 + g + 1) * 512 + lane * 8);
        }
#pragma unroll
        for (int nt = 0; nt < 4; ++nt)
#pragma unroll
          for (int rt = 0; rt < 4; ++rt)
            accO[rt][nt] = MFMA16(afC[g & 1][rt], bfC[g & 1][nt], accO[rt][nt]);
      }
    }
    // no barrier: next phase A writes sQ/sK/sVT (readers done before barrier 2);
    // sPO next written in phase B after its barrier 1.
  }

  // ============= epilogue: bias + coalesced store via LDS ==================
  __syncthreads();  // all waves done reading sHeads in phase C
  float bias_r[4];
#pragma unroll
  for (int nt = 0; nt < 4; ++nt) bias_r[nt] = bproj[wid * 64 + nt * 16 + lr];
  float* sEp = (float*)&sHeads[0][0][0];  // 64 KB = [32][512] f32
  size_t base = (size_t)blockIdx.x * (64 * 512);
#pragma unroll
  for (int half = 0; half < 2; ++half) {
#pragma unroll
    for (int rr = 0; rr < 2; ++rr) {
      int rt = half * 2 + rr;
#pragma unroll
      for (int nt = 0; nt < 4; ++nt)
#pragma unroll
        for (int rg = 0; rg < 4; ++rg) {
          int r = rr * 16 + lg * 4 + rg;  // local row 0..31
          int c = wid * 64 + nt * 16 + lr;
          sEp[r * 512 + (c ^ (((r >> 2) & 1) << 4))] = accO[rt][nt][rg] + bias_r[nt];
        }
    }
    __syncthreads();
#pragma unroll
    for (int j = 0; j < 8; ++j) {
      int f4 = tid + j * 512;
      int r = f4 >> 7;                 // local row 0..31
      int c0 = (f4 & 127) << 2;        // col 0..508
      float4 v = *(const float4*)&sEp[r * 512 + (c0 ^ (((r >> 2) & 1) << 4))];
      *(float4*)&out[base + (size_t)(half * 32 + r) * 512 + c0] = v;
    }
    if (half == 0) __syncthreads();
  }
}

extern "C" void kernel_launch(void* const* d_in, const int* in_sizes, int n_in,
                              void* d_out, int out_size, void* d_ws, size_t ws_size,
                              hipStream_t stream) {
  const float* x = (const float*)d_in[0];
  const float* Wqkv = (const float*)d_in[1];
  const float* Wproj = (const float*)d_in[2];
  const float* bproj = (const float*)d_in[3];
  float* out = (float*)d_out;

  _Float16* wqkvP = (_Float16*)d_ws;             // 786432 fp16 = 1.5 MB
  _Float16* wprojP = wqkvP + 786432;             // 262144 fp16 = 0.5 MB

  prep_weights<<<dim3(4096), dim3(256), 0, stream>>>(Wqkv, Wproj, wqkvP, wprojP);
  attn_fused<<<dim3(1024), dim3(512), 0, stream>>>(x, wqkvP, wprojP, bproj, out);
}